// Round 12
// baseline (2444.298 us; speedup 1.0000x reference)
//
#include <hip/hip_runtime.h>

#define B_ 1024
#define T_ 366
#define NS_ 365
#define CD_ 24

__device__ __forceinline__ float sigm(float x) { return __fdividef(1.f, 1.f + __expf(-x)); }
__device__ __forceinline__ float rl(float v, int k) {
    return __int_as_float(__builtin_amdgcn_readlane(__float_as_int(v), k));
}

// Non-rematerializable 16B load (asm origin is opaque -> must stay resident).
__device__ __forceinline__ float4 gld4(const float* p) {
    float4 r;
    asm volatile("global_load_dwordx4 %0, %1, off\n\ts_waitcnt vmcnt(0)"
                 : "=v"(r) : "v"(p) : "memory");
    return r;
}

// ---- pack: Wpk[e][32] = {w0..23, rad, bias}; Apk[r][32] = {w0..28, bias} ----
__global__ void mclstm_pack(const float* __restrict__ Wr, const float* __restrict__ br,
                            const float* __restrict__ Wp, const float* __restrict__ bp,
                            const float* __restrict__ Wc, const float* __restrict__ bc,
                            const float* __restrict__ Wa, const float* __restrict__ ba,
                            float* __restrict__ Wpk, float* __restrict__ Apk) {
    const int e = blockIdx.x * 64 + threadIdx.x;
    if (e < 576) {
#pragma unroll
        for (int k = 0; k < 24; ++k) Wpk[e * 32 + k] = Wr[e * 29 + k];
        Wpk[e * 32 + 24] = Wr[e * 29 + 25];
        Wpk[e * 32 + 25] = br[e];
#pragma unroll
        for (int k = 26; k < 32; ++k) Wpk[e * 32 + k] = 0.f;
    } else if (e < 625) {
        const int r = e - 576;
#pragma unroll
        for (int k = 0; k < 29; ++k)
            Apk[r * 32 + k] = (r < 24) ? Wp[r * 29 + k] : (r < 48) ? Wc[(r - 24) * 29 + k] : Wa[k];
        Apk[r * 32 + 29] = (r < 24) ? bp[r] : (r < 48) ? bc[r - 24] : ba[0];
        Apk[r * 32 + 30] = 0.f; Apk[r * 32 + 31] = 0.f;
    }
}

// ---- main: 2 chains per 256-thread block (4 waves); shared dots; asm weights ----
__global__ __attribute__((amdgpu_flat_work_group_size(256, 256), amdgpu_waves_per_eu(2, 2)))
void mclstm_main(const float* __restrict__ X, const float* __restrict__ ORY,
                 const float* __restrict__ Wpk, const float* __restrict__ Apk,
                 const float* __restrict__ c2a, const float* __restrict__ g2y,
                 float* __restrict__ allday, float* __restrict__ Ccell,
                 float* __restrict__ Cconv)
{
    __shared__ float zb[2][2][600];                  // [ch][kind][r*25+c]
    __shared__ __align__(16) float pb[2][2][672];    // [ch][kind][c*28+r]
    __shared__ __align__(16) float cbuf[2][24];
    __shared__ float cmb[2][24];

    const int tid = threadIdx.x;
    const int wv = tid >> 6, l = tid & 63;
    const int b0 = blockIdx.x * 2;

    // two register rows per lane (asm loads)
    float w1[24], w1r, b1, w2[24], w2r, b2;
    {
        const float* p1 = Wpk + (size_t)tid * 32;
        const float* p2 = Wpk + (size_t)(tid + 256) * 32;
#pragma unroll
        for (int q = 0; q < 6; ++q) {
            const float4 v = gld4(p1 + 4 * q);
            w1[4*q] = v.x; w1[4*q+1] = v.y; w1[4*q+2] = v.z; w1[4*q+3] = v.w;
            const float4 u = gld4(p2 + 4 * q);
            w2[4*q] = u.x; w2[4*q+1] = u.y; w2[4*q+2] = u.z; w2[4*q+3] = u.w;
        }
        const float4 t1 = gld4(p1 + 24); w1r = t1.x; b1 = t1.y;
        const float4 t2 = gld4(p2 + 24); w2r = t2.x; b2 = t2.y;
    }
    const int za1 = ((tid) / 24) * 25 + (tid) % 24;
    const int za2 = ((tid + 256) / 24) * 25 + (tid + 256) % 24;

    // union extra row: wave3 = redis 512+l; waves1/2 = aux row min(l,48); wave0 unused
    float ext[32];
    {
        const float* p = (wv == 3) ? (Wpk + (size_t)(512 + l) * 32)
                                   : (Apk + (size_t)((l < 49) ? l : 48) * 32);
#pragma unroll
        for (int q = 0; q < 8; ++q) {
            const float4 v = gld4(p + 4 * q);
            ext[4*q] = v.x; ext[4*q+1] = v.y; ext[4*q+2] = v.z; ext[4*q+3] = v.w;
        }
    }
    const int za3 = ((512 + l) / 24) * 25 + (512 + l) % 24;

    // aux chain ownership: wave1 -> chain0, wave2 -> chain1
    const int jA = (wv == 2) ? 1 : 0;
    const float* xj = X + (size_t)(b0 + jA) * T_ * 4;
    const float* oj = ORY + (size_t)(b0 + jA) * T_ * 7;

    // phase B/C decode: wave = 2*chain + kind
    const int jBC = wv >> 1, kBC = wv & 1;
    const int rc = l >> 1, hh = l & 1;

    // allday constants (kind0 waves, even lanes hold col l>>1)
    const bool evn = ((l & 1) == 0) && (l < 48);
    const float c2 = (kBC == 0 && evn) ? c2a[l >> 1] : 0.f;
    const float gy = (kBC == 0 && evn && l >= 32) ? g2y[(l >> 1) - 16] : 0.f;

    if (tid < 48) ((float*)cbuf)[tid] = 0.f;
    if (wv < 2 && l < 7)
        allday[(size_t)(b0 + wv) * T_ * 7 + l] = ORY[(size_t)(b0 + wv) * T_ * 7 + l];
    __syncthreads();

    float Ncum = 0.f, rp0 = 0.f, rp1 = 0.f;

    for (int u = 0; u <= NS_; ++u) {
        const bool do1 = (u < NS_), doCv = (u > 0);
        const int uu = do1 ? u : (NS_ - 1);
        const float ra0 = X[(size_t)b0 * T_ * 4 + uu * 4];
        const float ra1 = X[(size_t)(b0 + 1) * T_ * 4 + uu * 4];

        // both chains' C (LDS broadcast b128)
        float Cs0[24], Cs1[24];
#pragma unroll
        for (int q = 0; q < 6; ++q) {
            const float4 v0 = ((const float4*)cbuf[0])[q];
            const float4 v1 = ((const float4*)cbuf[1])[q];
            Cs0[4*q]=v0.x; Cs0[4*q+1]=v0.y; Cs0[4*q+2]=v0.z; Cs0[4*q+3]=v0.w;
            Cs1[4*q]=v1.x; Cs1[4*q+1]=v1.y; Cs1[4*q+2]=v1.z; Cs1[4*q+3]=v1.w;
        }

        // ---- Phase A: shared dots (row x 2 chains) ----
        {
            float d00 = b1, d01 = b1, d10 = b2, d11 = b2;
#pragma unroll
            for (int k = 0; k < 24; ++k) {
                d00 = fmaf(w1[k], Cs0[k], d00);
                d01 = fmaf(w1[k], Cs1[k], d01);
                d10 = fmaf(w2[k], Cs0[k], d10);
                d11 = fmaf(w2[k], Cs1[k], d11);
            }
            if (do1) {
                zb[0][0][za1] = fmaf(w1r, ra0, d00);
                zb[1][0][za1] = fmaf(w1r, ra1, d01);
                zb[0][0][za2] = fmaf(w2r, ra0, d10);
                zb[1][0][za2] = fmaf(w2r, ra1, d11);
            }
            if (doCv) {
                zb[0][1][za1] = fmaf(w1r, rp0, d00);
                zb[1][1][za1] = fmaf(w1r, rp1, d01);
                zb[0][1][za2] = fmaf(w2r, rp0, d10);
                zb[1][1][za2] = fmaf(w2r, rp1, d11);
            }
        }
        if (wv == 3) {                       // extra redis rows 512..575
            float d0 = ext[25], d1 = ext[25];
#pragma unroll
            for (int k = 0; k < 24; ++k) {
                d0 = fmaf(ext[k], Cs0[k], d0);
                d1 = fmaf(ext[k], Cs1[k], d1);
            }
            if (do1) {
                zb[0][0][za3] = fmaf(ext[24], ra0, d0);
                zb[1][0][za3] = fmaf(ext[24], ra1, d1);
            }
            if (doCv) {
                zb[0][1][za3] = fmaf(ext[24], rp0, d0);
                zb[1][1][za3] = fmaf(ext[24], rp1, d1);
            }
        } else if ((wv == 1 || wv == 2) && do1) {
            // aux row + in-wave part/cons/assim -> cmid for chain jA
            const float radc = (jA == 0) ? ra0 : ra1;
            const float tmx = xj[uu * 4 + 1], tmn = xj[uu * 4 + 2];
            Ncum += xj[uu * 4 + 3];
            const float dvs = oj[uu * 7];
            const float tave = 0.5f * (tmx + tmn);
            const float clm = fminf(fmaxf(tave * 50.f, 10.f), 40.f);
            const float eff = 0.54f - (clm - 10.f) * (0.18f / 30.f);
            const float cpot = radc * (eff * (2.f * 0.5f / 3.6f * (12.f / 44.f)));

            const float* Cj = (jA == 0) ? Cs0 : Cs1;
            float z = ext[29];
#pragma unroll
            for (int k = 0; k < 24; ++k) z = fmaf(ext[k], Cj[k], z);
            z = fmaf(ext[24], dvs, z);
            z = fmaf(ext[25], radc, z);
            z = fmaf(ext[26], tmx, z);
            z = fmaf(ext[27], tmn, z);
            z = fmaf(ext[28], Ncum, z);

            float pm = (l < 24) ? z : -1e30f;
#pragma unroll
            for (int o = 1; o < 32; o <<= 1) pm = fmaxf(pm, __shfl_xor(pm, o, 32));
            float pe = (l < 24) ? __expf(z - pm) : 0.f;
            float ps = pe;
#pragma unroll
            for (int o = 1; o < 32; o <<= 1) ps += __shfl_xor(ps, o, 32);
            const float conz = __shfl(z, 24 + (l & 31), 64);
            const float asmz = __shfl(z, 48, 64);
            if (l < 24) {
                const float part = __fdividef(pe, ps);
                cmb[jA][l] = (Cj[l] + sigm(asmz) * cpot * part) * (1.f - sigm(conz));
            }
        }
        __syncthreads();   // B1: zb + cmb ready

        // ---- Phase B: row softmax; wave (2j+k), 2 lanes/row ----
        {
            const bool act = (l < 48) && (kBC ? doCv : do1);
            if (act) {
                float z[12];
#pragma unroll
                for (int i = 0; i < 12; ++i) z[i] = zb[jBC][kBC][rc * 25 + hh * 12 + i];
                float m = z[0];
#pragma unroll
                for (int i = 1; i < 12; ++i) m = fmaxf(m, z[i]);
                m = fmaxf(m, __shfl_xor(m, 1));
                float ss = 0.f;
#pragma unroll
                for (int i = 0; i < 12; ++i) { z[i] = __expf(z[i] - m); ss += z[i]; }
                ss += __shfl_xor(ss, 1);
                const float mlt = kBC ? cbuf[jBC][rc] : cmb[jBC][rc];
                const float f = __fdividef(mlt, ss);
#pragma unroll
                for (int i = 0; i < 12; ++i) pb[jBC][kBC][(hh * 12 + i) * 28 + rc] = z[i] * f;
            }
        }
        __syncthreads();   // B2: scaled P ready

        // ---- Phase C: colsum (2 lanes/col) + outputs + folded all_day ----
        {
            const bool act = (l < 48) && (kBC ? doCv : do1);
            float ssum = 0.f;
            if (act) {
                const float4* p4 = (const float4*)&pb[jBC][kBC][rc * 28 + hh * 12];
#pragma unroll
                for (int i = 0; i < 3; ++i) {
                    const float4 v = p4[i];
                    ssum += (v.x + v.y) + (v.z + v.w);
                }
                ssum += __shfl_xor(ssum, 1);
                if (hh == 0) {
                    if (kBC) {
                        Cconv[((size_t)(b0 + jBC) * NS_ + (u - 1)) * CD_ + rc] = ssum;
                    } else {
                        cbuf[jBC][rc] = ssum;
                        Ccell[((size_t)(b0 + jBC) * NS_ + u) * CD_ + rc] = ssum;
                    }
                }
            }
            if (kBC == 0 && do1) {
                const float cv = evn ? ssum : 0.f;
                const float pv = fabsf(cv * c2);
                const float yv = fabsf(cv * gy);
                float a16 = cv, p16 = pv, y16 = yv;
#pragma unroll
                for (int o = 1; o < 16; o <<= 1) {
                    a16 += __shfl_xor(a16, o, 16);
                    p16 += __shfl_xor(p16, o, 16);
                    y16 += __shfl_xor(y16, o, 16);
                }
                const float pai = rl(p16, 0) + rl(p16, 16) + rl(p16, 32);
                const float lea = rl(a16, 0)  * (1.f / 0.419f);
                const float ste = rl(a16, 16) * (1.f / 0.431f);
                const float gra = rl(a16, 32) * (1.f / 0.487f);
                const float yie = rl(y16, 32) * (1.f / 0.487f);
                const float agb = lea + ste + gra;
                const float dvsn = ORY[((size_t)(b0 + jBC) * T_ + (u + 1)) * 7];
                if (l < 7) {
                    float val = dvsn;
                    val = (l == 1) ? pai : val;
                    val = (l == 2) ? lea : val;
                    val = (l == 3) ? ste : val;
                    val = (l == 4) ? gra : val;
                    val = (l == 5) ? agb : val;
                    val = (l == 6) ? yie : val;
                    allday[((size_t)(b0 + jBC) * T_ + (u + 1)) * 7 + l] = val;
                }
            }
        }
        __syncthreads();   // B3: C(t+1) visible
        rp0 = ra0; rp1 = ra1;
    }
}

extern "C" void kernel_launch(void* const* d_in, const int* in_sizes, int n_in,
                              void* d_out, int out_size, void* d_ws, size_t ws_size,
                              hipStream_t stream) {
    const float* X   = (const float*)d_in[0];
    const float* ORY = (const float*)d_in[1];
    const float* Wr  = (const float*)d_in[2];
    const float* br  = (const float*)d_in[3];
    const float* Wp  = (const float*)d_in[4];
    const float* bp  = (const float*)d_in[5];
    const float* Wc  = (const float*)d_in[6];
    const float* bc  = (const float*)d_in[7];
    const float* Wa  = (const float*)d_in[8];
    const float* ba  = (const float*)d_in[9];
    const float* c2a = (const float*)d_in[10];
    const float* g2y = (const float*)d_in[11];

    float* allday = (float*)d_out;
    float* Ccell  = allday + (size_t)B_ * T_ * 7;
    float* Cconv  = Ccell + (size_t)B_ * NS_ * CD_;

    float* Wpk = (float*)d_ws;            // 576*32 floats
    float* Apk = Wpk + 576 * 32;          // 49*32 floats

    hipLaunchKernelGGL(mclstm_pack, dim3(10), dim3(64), 0, stream,
                       Wr, br, Wp, bp, Wc, bc, Wa, ba, Wpk, Apk);
    hipLaunchKernelGGL(mclstm_main, dim3(B_ / 2), dim3(256), 0, stream,
                       X, ORY, Wpk, Apk, c2a, g2y, allday, Ccell, Cconv);
}

// Round 13
// 2440.832 us; speedup vs baseline: 1.0014x; 1.0014x over previous
//
#include <hip/hip_runtime.h>

#define B_ 1024
#define T_ 366
#define NS_ 365
#define CD_ 24

__device__ __forceinline__ float sigm(float x) { return __fdividef(1.f, 1.f + __expf(-x)); }
__device__ __forceinline__ float rl(float v, int k) {
    return __int_as_float(__builtin_amdgcn_readlane(__float_as_int(v), k));
}

// Non-rematerializable 16B load (asm origin is opaque -> must stay resident).
__device__ __forceinline__ float4 gld4(const float* p) {
    float4 r;
    asm volatile("global_load_dwordx4 %0, %1, off\n\ts_waitcnt vmcnt(0)"
                 : "=v"(r) : "v"(p) : "memory");
    return r;
}

// ---- pack: Wpk[e][32] = {w0..23, rad, bias}; Apk[r][32] = {w0..28, bias} ----
__global__ void mclstm_pack(const float* __restrict__ Wr, const float* __restrict__ br,
                            const float* __restrict__ Wp, const float* __restrict__ bp,
                            const float* __restrict__ Wc, const float* __restrict__ bc,
                            const float* __restrict__ Wa, const float* __restrict__ ba,
                            float* __restrict__ Wpk, float* __restrict__ Apk) {
    const int e = blockIdx.x * 64 + threadIdx.x;
    if (e < 576) {
#pragma unroll
        for (int k = 0; k < 24; ++k) Wpk[e * 32 + k] = Wr[e * 29 + k];
        Wpk[e * 32 + 24] = Wr[e * 29 + 25];
        Wpk[e * 32 + 25] = br[e];
#pragma unroll
        for (int k = 26; k < 32; ++k) Wpk[e * 32 + k] = 0.f;
    } else if (e < 625) {
        const int r = e - 576;
#pragma unroll
        for (int k = 0; k < 29; ++k)
            Apk[r * 32 + k] = (r < 24) ? Wp[r * 29 + k] : (r < 48) ? Wc[(r - 24) * 29 + k] : Wa[k];
        Apk[r * 32 + 29] = (r < 24) ? bp[r] : (r < 48) ? bc[r - 24] : ba[0];
        Apk[r * 32 + 30] = 0.f; Apk[r * 32 + 31] = 0.f;
    }
}

// ---- main: 2 chains per 256-thread block (4 waves); shared dots; asm weights ----
__global__ __attribute__((amdgpu_flat_work_group_size(256, 256), amdgpu_waves_per_eu(2, 2)))
void mclstm_main(const float* __restrict__ X, const float* __restrict__ ORY,
                 const float* __restrict__ Wpk, const float* __restrict__ Apk,
                 const float* __restrict__ c2a, const float* __restrict__ g2y,
                 float* __restrict__ allday, float* __restrict__ Ccell,
                 float* __restrict__ Cconv)
{
    __shared__ float zb[2][2][600];                  // [ch][kind][r*25+c]
    __shared__ __align__(16) float pb[2][2][672];    // [ch][kind][c*28+r]
    __shared__ __align__(16) float cbuf[2][24];
    __shared__ float cmb[2][24];

    const int tid = threadIdx.x;
    const int wv = tid >> 6, l = tid & 63;
    const int b0 = blockIdx.x * 2;

    // two register rows per lane (asm loads)
    float w1[24], w1r, b1, w2[24], w2r, b2;
    {
        const float* p1 = Wpk + (size_t)tid * 32;
        const float* p2 = Wpk + (size_t)(tid + 256) * 32;
#pragma unroll
        for (int q = 0; q < 6; ++q) {
            const float4 v = gld4(p1 + 4 * q);
            w1[4*q] = v.x; w1[4*q+1] = v.y; w1[4*q+2] = v.z; w1[4*q+3] = v.w;
            const float4 u = gld4(p2 + 4 * q);
            w2[4*q] = u.x; w2[4*q+1] = u.y; w2[4*q+2] = u.z; w2[4*q+3] = u.w;
        }
        const float4 t1 = gld4(p1 + 24); w1r = t1.x; b1 = t1.y;
        const float4 t2 = gld4(p2 + 24); w2r = t2.x; b2 = t2.y;
    }
    const int za1 = ((tid) / 24) * 25 + (tid) % 24;
    const int za2 = ((tid + 256) / 24) * 25 + (tid + 256) % 24;

    // union extra row: wave3 = redis 512+l; waves1/2 = aux row min(l,48); wave0 unused
    float ext[32];
    {
        const float* p = (wv == 3) ? (Wpk + (size_t)(512 + l) * 32)
                                   : (Apk + (size_t)((l < 49) ? l : 48) * 32);
#pragma unroll
        for (int q = 0; q < 8; ++q) {
            const float4 v = gld4(p + 4 * q);
            ext[4*q] = v.x; ext[4*q+1] = v.y; ext[4*q+2] = v.z; ext[4*q+3] = v.w;
        }
    }
    const int za3 = ((512 + l) / 24) * 25 + (512 + l) % 24;

    // aux chain ownership: wave1 -> chain0, wave2 -> chain1
    const int jA = (wv == 2) ? 1 : 0;
    const float* xj = X + (size_t)(b0 + jA) * T_ * 4;
    const float* oj = ORY + (size_t)(b0 + jA) * T_ * 7;

    // phase B/C decode: wave = 2*chain + kind
    const int jBC = wv >> 1, kBC = wv & 1;
    const int rc = l >> 1, hh = l & 1;

    // allday constants (kind0 waves, even lanes hold col l>>1)
    const bool evn = ((l & 1) == 0) && (l < 48);
    const float c2 = (kBC == 0 && evn) ? c2a[l >> 1] : 0.f;
    const float gy = (kBC == 0 && evn && l >= 32) ? g2y[(l >> 1) - 16] : 0.f;

    if (tid < 48) ((float*)cbuf)[tid] = 0.f;
    if (wv < 2 && l < 7)
        allday[(size_t)(b0 + wv) * T_ * 7 + l] = ORY[(size_t)(b0 + wv) * T_ * 7 + l];
    __syncthreads();

    float Ncum = 0.f, rp0 = 0.f, rp1 = 0.f;

    for (int u = 0; u <= NS_; ++u) {
        const bool do1 = (u < NS_), doCv = (u > 0);
        const int uu = do1 ? u : (NS_ - 1);
        const float ra0 = X[(size_t)b0 * T_ * 4 + uu * 4];
        const float ra1 = X[(size_t)(b0 + 1) * T_ * 4 + uu * 4];

        // both chains' C (LDS broadcast b128)
        float Cs0[24], Cs1[24];
#pragma unroll
        for (int q = 0; q < 6; ++q) {
            const float4 v0 = ((const float4*)cbuf[0])[q];
            const float4 v1 = ((const float4*)cbuf[1])[q];
            Cs0[4*q]=v0.x; Cs0[4*q+1]=v0.y; Cs0[4*q+2]=v0.z; Cs0[4*q+3]=v0.w;
            Cs1[4*q]=v1.x; Cs1[4*q+1]=v1.y; Cs1[4*q+2]=v1.z; Cs1[4*q+3]=v1.w;
        }

        // ---- Phase A: shared dots (row x 2 chains) ----
        {
            float d00 = b1, d01 = b1, d10 = b2, d11 = b2;
#pragma unroll
            for (int k = 0; k < 24; ++k) {
                d00 = fmaf(w1[k], Cs0[k], d00);
                d01 = fmaf(w1[k], Cs1[k], d01);
                d10 = fmaf(w2[k], Cs0[k], d10);
                d11 = fmaf(w2[k], Cs1[k], d11);
            }
            if (do1) {
                zb[0][0][za1] = fmaf(w1r, ra0, d00);
                zb[1][0][za1] = fmaf(w1r, ra1, d01);
                zb[0][0][za2] = fmaf(w2r, ra0, d10);
                zb[1][0][za2] = fmaf(w2r, ra1, d11);
            }
            if (doCv) {
                zb[0][1][za1] = fmaf(w1r, rp0, d00);
                zb[1][1][za1] = fmaf(w1r, rp1, d01);
                zb[0][1][za2] = fmaf(w2r, rp0, d10);
                zb[1][1][za2] = fmaf(w2r, rp1, d11);
            }
        }
        if (wv == 3) {                       // extra redis rows 512..575
            float d0 = ext[25], d1 = ext[25];
#pragma unroll
            for (int k = 0; k < 24; ++k) {
                d0 = fmaf(ext[k], Cs0[k], d0);
                d1 = fmaf(ext[k], Cs1[k], d1);
            }
            if (do1) {
                zb[0][0][za3] = fmaf(ext[24], ra0, d0);
                zb[1][0][za3] = fmaf(ext[24], ra1, d1);
            }
            if (doCv) {
                zb[0][1][za3] = fmaf(ext[24], rp0, d0);
                zb[1][1][za3] = fmaf(ext[24], rp1, d1);
            }
        } else if ((wv == 1 || wv == 2) && do1) {
            // aux row + in-wave part/cons/assim -> cmid for chain jA
            const float radc = (jA == 0) ? ra0 : ra1;
            const float tmx = xj[uu * 4 + 1], tmn = xj[uu * 4 + 2];
            Ncum += xj[uu * 4 + 3];
            const float dvs = oj[uu * 7];
            const float tave = 0.5f * (tmx + tmn);
            const float clm = fminf(fmaxf(tave * 50.f, 10.f), 40.f);
            const float eff = 0.54f - (clm - 10.f) * (0.18f / 30.f);
            const float cpot = radc * (eff * (2.f * 0.5f / 3.6f * (12.f / 44.f)));

            const float* Cj = (jA == 0) ? Cs0 : Cs1;
            float z = ext[29];
#pragma unroll
            for (int k = 0; k < 24; ++k) z = fmaf(ext[k], Cj[k], z);
            z = fmaf(ext[24], dvs, z);
            z = fmaf(ext[25], radc, z);
            z = fmaf(ext[26], tmx, z);
            z = fmaf(ext[27], tmn, z);
            z = fmaf(ext[28], Ncum, z);

            float pm = (l < 24) ? z : -1e30f;
#pragma unroll
            for (int o = 1; o < 32; o <<= 1) pm = fmaxf(pm, __shfl_xor(pm, o, 32));
            float pe = (l < 24) ? __expf(z - pm) : 0.f;
            float ps = pe;
#pragma unroll
            for (int o = 1; o < 32; o <<= 1) ps += __shfl_xor(ps, o, 32);
            const float conz = __shfl(z, 24 + (l & 31), 64);
            const float asmz = __shfl(z, 48, 64);
            if (l < 24) {
                const float part = __fdividef(pe, ps);
                cmb[jA][l] = (Cj[l] + sigm(asmz) * cpot * part) * (1.f - sigm(conz));
            }
        }
        __syncthreads();   // B1: zb + cmb ready

        // ---- Phase B: row softmax; wave (2j+k), 2 lanes/row ----
        {
            const bool act = (l < 48) && (kBC ? doCv : do1);
            if (act) {
                float z[12];
#pragma unroll
                for (int i = 0; i < 12; ++i) z[i] = zb[jBC][kBC][rc * 25 + hh * 12 + i];
                float m = z[0];
#pragma unroll
                for (int i = 1; i < 12; ++i) m = fmaxf(m, z[i]);
                m = fmaxf(m, __shfl_xor(m, 1));
                float ss = 0.f;
#pragma unroll
                for (int i = 0; i < 12; ++i) { z[i] = __expf(z[i] - m); ss += z[i]; }
                ss += __shfl_xor(ss, 1);
                const float mlt = kBC ? cbuf[jBC][rc] : cmb[jBC][rc];
                const float f = __fdividef(mlt, ss);
#pragma unroll
                for (int i = 0; i < 12; ++i) pb[jBC][kBC][(hh * 12 + i) * 28 + rc] = z[i] * f;
            }
        }
        __syncthreads();   // B2: scaled P ready

        // ---- Phase C: colsum (2 lanes/col) + outputs + folded all_day ----
        {
            const bool act = (l < 48) && (kBC ? doCv : do1);
            float ssum = 0.f;
            if (act) {
                const float4* p4 = (const float4*)&pb[jBC][kBC][rc * 28 + hh * 12];
#pragma unroll
                for (int i = 0; i < 3; ++i) {
                    const float4 v = p4[i];
                    ssum += (v.x + v.y) + (v.z + v.w);
                }
                ssum += __shfl_xor(ssum, 1);
                if (hh == 0) {
                    if (kBC) {
                        Cconv[((size_t)(b0 + jBC) * NS_ + (u - 1)) * CD_ + rc] = ssum;
                    } else {
                        cbuf[jBC][rc] = ssum;
                        Ccell[((size_t)(b0 + jBC) * NS_ + u) * CD_ + rc] = ssum;
                    }
                }
            }
            if (kBC == 0 && do1) {
                const float cv = evn ? ssum : 0.f;
                const float pv = fabsf(cv * c2);
                const float yv = fabsf(cv * gy);
                float a16 = cv, p16 = pv, y16 = yv;
#pragma unroll
                for (int o = 1; o < 16; o <<= 1) {
                    a16 += __shfl_xor(a16, o, 16);
                    p16 += __shfl_xor(p16, o, 16);
                    y16 += __shfl_xor(y16, o, 16);
                }
                const float pai = rl(p16, 0) + rl(p16, 16) + rl(p16, 32);
                const float lea = rl(a16, 0)  * (1.f / 0.419f);
                const float ste = rl(a16, 16) * (1.f / 0.431f);
                const float gra = rl(a16, 32) * (1.f / 0.487f);
                const float yie = rl(y16, 32) * (1.f / 0.487f);
                const float agb = lea + ste + gra;
                const float dvsn = ORY[((size_t)(b0 + jBC) * T_ + (u + 1)) * 7];
                if (l < 7) {
                    float val = dvsn;
                    val = (l == 1) ? pai : val;
                    val = (l == 2) ? lea : val;
                    val = (l == 3) ? ste : val;
                    val = (l == 4) ? gra : val;
                    val = (l == 5) ? agb : val;
                    val = (l == 6) ? yie : val;
                    allday[((size_t)(b0 + jBC) * T_ + (u + 1)) * 7 + l] = val;
                }
            }
        }
        __syncthreads();   // B3: C(t+1) visible
        rp0 = ra0; rp1 = ra1;
    }
}

extern "C" void kernel_launch(void* const* d_in, const int* in_sizes, int n_in,
                              void* d_out, int out_size, void* d_ws, size_t ws_size,
                              hipStream_t stream) {
    const float* X   = (const float*)d_in[0];
    const float* ORY = (const float*)d_in[1];
    const float* Wr  = (const float*)d_in[2];
    const float* br  = (const float*)d_in[3];
    const float* Wp  = (const float*)d_in[4];
    const float* bp  = (const float*)d_in[5];
    const float* Wc  = (const float*)d_in[6];
    const float* bc  = (const float*)d_in[7];
    const float* Wa  = (const float*)d_in[8];
    const float* ba  = (const float*)d_in[9];
    const float* c2a = (const float*)d_in[10];
    const float* g2y = (const float*)d_in[11];

    float* allday = (float*)d_out;
    float* Ccell  = allday + (size_t)B_ * T_ * 7;
    float* Cconv  = Ccell + (size_t)B_ * NS_ * CD_;

    float* Wpk = (float*)d_ws;            // 576*32 floats
    float* Apk = Wpk + 576 * 32;          // 49*32 floats

    hipLaunchKernelGGL(mclstm_pack, dim3(10), dim3(64), 0, stream,
                       Wr, br, Wp, bp, Wc, bc, Wa, ba, Wpk, Apk);
    hipLaunchKernelGGL(mclstm_main, dim3(B_ / 2), dim3(256), 0, stream,
                       X, ORY, Wpk, Apk, c2a, g2y, allday, Ccell, Cconv);
}

// Round 15
// 731.302 us; speedup vs baseline: 3.3424x; 3.3377x over previous
//
#include <hip/hip_runtime.h>

#define B_ 1024
#define T_ 366
#define NS_ 365
#define CD_ 24

__device__ __forceinline__ float sigm(float x) { return __fdividef(1.f, 1.f + __expf(-x)); }
__device__ __forceinline__ float rl(float v, int k) {
    return __int_as_float(__builtin_amdgcn_readlane(__float_as_int(v), k));
}

// ---- pack: Wpk[e][32] = {w0..23, rad, bias}; Apk[r][32] = {w0..28, bias} ----
__global__ void mclstm_pack(const float* __restrict__ Wr, const float* __restrict__ br,
                            const float* __restrict__ Wp, const float* __restrict__ bp,
                            const float* __restrict__ Wc, const float* __restrict__ bc,
                            const float* __restrict__ Wa, const float* __restrict__ ba,
                            float* __restrict__ Wpk, float* __restrict__ Apk) {
    const int e = blockIdx.x * 64 + threadIdx.x;
    if (e < 576) {
#pragma unroll
        for (int k = 0; k < 24; ++k) Wpk[e * 32 + k] = Wr[e * 29 + k];
        Wpk[e * 32 + 24] = Wr[e * 29 + 25];
        Wpk[e * 32 + 25] = br[e];
#pragma unroll
        for (int k = 26; k < 32; ++k) Wpk[e * 32 + k] = 0.f;
    } else if (e < 625) {
        const int r = e - 576;
#pragma unroll
        for (int k = 0; k < 29; ++k)
            Apk[r * 32 + k] = (r < 24) ? Wp[r * 29 + k] : (r < 48) ? Wc[(r - 24) * 29 + k] : Wa[k];
        Apk[r * 32 + 29] = (r < 24) ? bp[r] : (r < 48) ? bc[r - 24] : ba[0];
        Apk[r * 32 + 30] = 0.f; Apk[r * 32 + 31] = 0.f;
    }
}

// ---- main: 1 chain / 128-thr block; 4 redis rows per lane + ext row;
//      fused softmax+colsum; reg-prefetched X/ORY ----
__global__ __attribute__((amdgpu_flat_work_group_size(128, 128), amdgpu_waves_per_eu(2, 2)))
void mclstm_main(const float* __restrict__ X, const float* __restrict__ ORY,
                 const float* __restrict__ Wpk, const float* __restrict__ Apk,
                 const float* __restrict__ c2a, const float* __restrict__ g2y,
                 float* __restrict__ allday, float* __restrict__ Ccell,
                 float* __restrict__ Cconv)
{
    __shared__ __align__(16) float zb1[672], zb2[672];   // z row-major, stride 28
    __shared__ __align__(16) float pb1[672], pb2[672];   // scaled P col-major, stride 28
    __shared__ __align__(16) float cbuf[24];
    __shared__ float cmb[24];

    const int tid = threadIdx.x;
    const int l = tid & 63, wv = tid >> 6;
    const int b = blockIdx.x;

    // 4 register-resident redis rows: e = tid + 128*j (covers 0..511)
    float wrg[4][24], wrad[4], brg[4];
    int za[4];
#pragma unroll
    for (int j = 0; j < 4; ++j) {
        const int e = tid + 128 * j;
        const float4* wp = (const float4*)(Wpk + (size_t)e * 32);
#pragma unroll
        for (int q = 0; q < 6; ++q) {
            const float4 v = wp[q];
            wrg[j][4*q] = v.x; wrg[j][4*q+1] = v.y; wrg[j][4*q+2] = v.z; wrg[j][4*q+3] = v.w;
        }
        const float4 t = wp[6];
        wrad[j] = t.x; brg[j] = t.y;
        za[j] = (e / 24) * 28 + (e % 24);
    }
    // union extra row: wave0 = redis row 512+l; wave1 = aux row min(l,48)
    float ext[32];
    {
        const float4* p = (const float4*)((wv == 0) ? (Wpk + (size_t)(512 + l) * 32)
                                                    : (Apk + (size_t)((l < 49) ? l : 48) * 32));
#pragma unroll
        for (int q = 0; q < 8; ++q) {
            const float4 v = p[q];
            ext[4*q] = v.x; ext[4*q+1] = v.y; ext[4*q+2] = v.z; ext[4*q+3] = v.w;
        }
    }
    const int za4 = ((512 + l) / 24) * 28 + (512 + l) % 24;

    const int rc = l >> 1, hh = l & 1;
    // allday constants (wave0; even lanes <48 hold col l>>1)
    const bool evn = ((l & 1) == 0) && (l < 48);
    const float c2 = evn ? c2a[l >> 1] : 0.f;
    const float gy = (evn && l >= 32) ? g2y[(l >> 1) - 16] : 0.f;

    const float* xrow = X + (size_t)b * T_ * 4;
    const float* orow = ORY + (size_t)b * T_ * 7;

    if (tid < 7) allday[(size_t)b * T_ * 7 + tid] = orow[tid];
    if (tid < 24) cbuf[tid] = 0.f;
    __syncthreads();

    float Ncum = 0.f, rp = 0.f;
    float4 xc = *(const float4*)xrow;   // step-u X in registers
    float dvsc = orow[0];

    for (int u = 0; u <= NS_; ++u) {
        const bool do1 = (u < NS_), doCv = (u > 0);

        // prefetch step u+1 (hidden under the whole step)
        const int un = (u + 1 <= NS_) ? (u + 1) : NS_;
        const float4 xn = *(const float4*)(xrow + un * 4);
        const float dn = orow[un * 7];

        const float ra = xc.x;

        // C_u broadcast + kind1 multiplier captured pre-barrier
        float Cs[24];
#pragma unroll
        for (int q = 0; q < 6; ++q) {
            const float4 v = ((const float4*)cbuf)[q];
            Cs[4*q] = v.x; Cs[4*q+1] = v.y; Cs[4*q+2] = v.z; Cs[4*q+3] = v.w;
        }
        const float mlt1 = cbuf[rc];

        // ---- Phase A: shared dots (4 rows); z1 = D + wrad*ra, z2 = D + wrad*rp ----
#pragma unroll
        for (int j = 0; j < 4; ++j) {
            float p0 = brg[j], p1 = 0.f, p2 = 0.f, p3 = 0.f;
#pragma unroll
            for (int k = 0; k < 24; k += 4) {
                p0 = fmaf(wrg[j][k],   Cs[k],   p0);
                p1 = fmaf(wrg[j][k+1], Cs[k+1], p1);
                p2 = fmaf(wrg[j][k+2], Cs[k+2], p2);
                p3 = fmaf(wrg[j][k+3], Cs[k+3], p3);
            }
            const float D = (p0 + p1) + (p2 + p3);
            if (do1)  zb1[za[j]] = fmaf(wrad[j], ra, D);
            if (doCv) zb2[za[j]] = fmaf(wrad[j], rp, D);
        }

        if (wv == 0) {
            // 5th redis row (rows 512..575)
            float p0 = ext[25], p1 = 0.f, p2 = 0.f, p3 = 0.f;
#pragma unroll
            for (int k = 0; k < 24; k += 4) {
                p0 = fmaf(ext[k],   Cs[k],   p0);
                p1 = fmaf(ext[k+1], Cs[k+1], p1);
                p2 = fmaf(ext[k+2], Cs[k+2], p2);
                p3 = fmaf(ext[k+3], Cs[k+3], p3);
            }
            const float D = (p0 + p1) + (p2 + p3);
            if (do1)  zb1[za4] = fmaf(ext[24], ra, D);
            if (doCv) zb2[za4] = fmaf(ext[24], rp, D);
        } else if (do1) {
            // aux row + in-wave part/cons/assim -> cmid (lanes 0..23)
            Ncum += xc.w;
            const float tave = 0.5f * (xc.y + xc.z);
            const float clm = fminf(fmaxf(tave * 50.f, 10.f), 40.f);
            const float eff = 0.54f - (clm - 10.f) * (0.18f / 30.f);
            const float cpot = ra * (eff * (2.f * 0.5f / 3.6f * (12.f / 44.f)));

            float z = ext[29];
#pragma unroll
            for (int k = 0; k < 24; ++k) z = fmaf(ext[k], Cs[k], z);
            z = fmaf(ext[24], dvsc, z);
            z = fmaf(ext[25], ra, z);
            z = fmaf(ext[26], xc.y, z);
            z = fmaf(ext[27], xc.z, z);
            z = fmaf(ext[28], Ncum, z);

            float pm = (l < 24) ? z : -1e30f;
#pragma unroll
            for (int o = 1; o < 32; o <<= 1) pm = fmaxf(pm, __shfl_xor(pm, o, 32));
            float pe = (l < 24) ? __expf(z - pm) : 0.f;
            float ps = pe;
#pragma unroll
            for (int o = 1; o < 32; o <<= 1) ps += __shfl_xor(ps, o, 32);
            const float conz = __shfl(z, 24 + (l & 31), 64);
            const float asmz = __shfl(z, 48, 64);
            if (l < 24) {
                const float part = __fdividef(pe, ps);
                cmb[l] = (cbuf[l] + sigm(asmz) * cpot * part) * (1.f - sigm(conz));
            }
        }
        __syncthreads();   // B1: zb + cmb ready

        // ---- FUSED softmax + colsum: wave wv owns kind wv (same-wave LDS ordered) ----
        float ssum = 0.f;
        {
            const bool act = (l < 48) && (wv ? doCv : do1);
            if (act) {
                const float* zs = wv ? zb2 : zb1;
                float* pbk = wv ? pb2 : pb1;
                const float4* z4 = (const float4*)(zs + rc * 28 + hh * 12);
                float z[12];
#pragma unroll
                for (int q = 0; q < 3; ++q) {
                    const float4 v = z4[q];
                    z[4*q] = v.x; z[4*q+1] = v.y; z[4*q+2] = v.z; z[4*q+3] = v.w;
                }
                float m = z[0];
#pragma unroll
                for (int i = 1; i < 12; ++i) m = fmaxf(m, z[i]);
                m = fmaxf(m, __shfl_xor(m, 1));
                float ss = 0.f;
#pragma unroll
                for (int i = 0; i < 12; ++i) { z[i] = __expf(z[i] - m); ss += z[i]; }
                ss += __shfl_xor(ss, 1);
                const float mult = wv ? mlt1 : cmb[rc];
                const float f = __fdividef(mult, ss);
#pragma unroll
                for (int i = 0; i < 12; ++i) pbk[(hh * 12 + i) * 28 + rc] = z[i] * f;

                // colsum (same-wave RAW; HW orders LDS ops within a wave)
                const float4* p4 = (const float4*)(pbk + rc * 28 + hh * 12);
#pragma unroll
                for (int i = 0; i < 3; ++i) {
                    const float4 v = p4[i];
                    ssum += (v.x + v.y) + (v.z + v.w);
                }
                ssum += __shfl_xor(ssum, 1);
                if (hh == 0) {
                    if (wv) {
                        Cconv[((size_t)b * NS_ + (u - 1)) * CD_ + rc] = ssum;
                    } else {
                        cbuf[rc] = ssum;
                        Ccell[((size_t)b * NS_ + u) * CD_ + rc] = ssum;
                    }
                }
            }
        }
        // folded all_day (wave0; dvs(u+1) from prefetch regs)
        if (wv == 0 && do1) {
            const float cv = evn ? ssum : 0.f;
            const float pv = fabsf(cv * c2);
            const float yv = fabsf(cv * gy);
            float a16 = cv, p16 = pv, y16 = yv;
#pragma unroll
            for (int o = 1; o < 16; o <<= 1) {
                a16 += __shfl_xor(a16, o, 16);
                p16 += __shfl_xor(p16, o, 16);
                y16 += __shfl_xor(y16, o, 16);
            }
            const float pai = rl(p16, 0) + rl(p16, 16) + rl(p16, 32);
            const float lea = rl(a16, 0)  * (1.f / 0.419f);
            const float ste = rl(a16, 16) * (1.f / 0.431f);
            const float gra = rl(a16, 32) * (1.f / 0.487f);
            const float yie = rl(y16, 32) * (1.f / 0.487f);
            const float agb = lea + ste + gra;
            if (l < 7) {
                float val = dn;
                val = (l == 1) ? pai : val;
                val = (l == 2) ? lea : val;
                val = (l == 3) ? ste : val;
                val = (l == 4) ? gra : val;
                val = (l == 5) ? agb : val;
                val = (l == 6) ? yie : val;
                allday[((size_t)b * T_ + (u + 1)) * 7 + l] = val;
            }
        }
        __syncthreads();   // B2: C(t+1) visible; zb free for next step
        rp = ra; xc = xn; dvsc = dn;
    }
}

extern "C" void kernel_launch(void* const* d_in, const int* in_sizes, int n_in,
                              void* d_out, int out_size, void* d_ws, size_t ws_size,
                              hipStream_t stream) {
    const float* X   = (const float*)d_in[0];
    const float* ORY = (const float*)d_in[1];
    const float* Wr  = (const float*)d_in[2];
    const float* br  = (const float*)d_in[3];
    const float* Wp  = (const float*)d_in[4];
    const float* bp  = (const float*)d_in[5];
    const float* Wc  = (const float*)d_in[6];
    const float* bc  = (const float*)d_in[7];
    const float* Wa  = (const float*)d_in[8];
    const float* ba  = (const float*)d_in[9];
    const float* c2a = (const float*)d_in[10];
    const float* g2y = (const float*)d_in[11];

    float* allday = (float*)d_out;
    float* Ccell  = allday + (size_t)B_ * T_ * 7;
    float* Cconv  = Ccell + (size_t)B_ * NS_ * CD_;

    float* Wpk = (float*)d_ws;            // 576*32 floats
    float* Apk = Wpk + 576 * 32;          // 49*32 floats

    hipLaunchKernelGGL(mclstm_pack, dim3(10), dim3(64), 0, stream,
                       Wr, br, Wp, bp, Wc, bc, Wa, ba, Wpk, Apk);
    hipLaunchKernelGGL(mclstm_main, dim3(B_), dim3(128), 0, stream,
                       X, ORY, Wpk, Apk, c2a, g2y, allday, Ccell, Cconv);
}

// Round 16
// 678.620 us; speedup vs baseline: 3.6019x; 1.0776x over previous
//
#include <hip/hip_runtime.h>

#define B_ 1024
#define T_ 366
#define NS_ 365
#define CD_ 24
#define NTASK (B_ * NS_)

__device__ __forceinline__ float sigm2(float x) {   // x pre-scaled by log2(e)
    return __fdividef(1.f, 1.f + exp2f(-x));
}
__device__ __forceinline__ float rl(float v, int k) {
    return __int_as_float(__builtin_amdgcn_readlane(__float_as_int(v), k));
}

// ---- pack (weights pre-scaled by log2e so gates use native exp2):
//      Wpk[e][32] = {w0..23, rad, bias}; Apk[r][32] = {w0..28, bias} ----
__global__ void mclstm_pack(const float* __restrict__ Wr, const float* __restrict__ br,
                            const float* __restrict__ Wp, const float* __restrict__ bp,
                            const float* __restrict__ Wc, const float* __restrict__ bc,
                            const float* __restrict__ Wa, const float* __restrict__ ba,
                            float* __restrict__ Wpk, float* __restrict__ Apk) {
    const float S = 1.44269504088896341f;   // log2(e)
    const int e = blockIdx.x * 64 + threadIdx.x;
    if (e < 576) {
#pragma unroll
        for (int k = 0; k < 24; ++k) Wpk[e * 32 + k] = Wr[e * 29 + k] * S;
        Wpk[e * 32 + 24] = Wr[e * 29 + 25] * S;
        Wpk[e * 32 + 25] = br[e] * S;
#pragma unroll
        for (int k = 26; k < 32; ++k) Wpk[e * 32 + k] = 0.f;
    } else if (e < 625) {
        const int r = e - 576;
#pragma unroll
        for (int k = 0; k < 29; ++k)
            Apk[r * 32 + k] = ((r < 24) ? Wp[r * 29 + k] : (r < 48) ? Wc[(r - 24) * 29 + k] : Wa[k]) * S;
        Apk[r * 32 + 29] = ((r < 24) ? bp[r] : (r < 48) ? bc[r - 24] : ba[0]) * S;
        Apk[r * 32 + 30] = 0.f; Apk[r * 32 + 31] = 0.f;
    }
}

// ---- main: 1 chain / 128-thr block; 4 redis rows/lane + ext row;
//      fused softmax+colsum; reg-prefetched X/ORY; no all_day in loop ----
__global__ __attribute__((amdgpu_flat_work_group_size(128, 128), amdgpu_waves_per_eu(2, 2)))
void mclstm_main(const float* __restrict__ X, const float* __restrict__ ORY,
                 const float* __restrict__ Wpk, const float* __restrict__ Apk,
                 float* __restrict__ Ccell, float* __restrict__ Cconv)
{
    __shared__ __align__(16) float zb1[672], zb2[672];   // z row-major, stride 28
    __shared__ __align__(16) float pb1[672], pb2[672];   // scaled P col-major, stride 28
    __shared__ __align__(16) float cbuf[24];
    __shared__ float cmb[24];

    const int tid = threadIdx.x;
    const int l = tid & 63, wv = tid >> 6;
    const int b = blockIdx.x;

    // 4 register-resident redis rows: e = tid + 128*j (covers 0..511)
    float wrg[4][24], wrad[4], brg[4];
    int za[4];
#pragma unroll
    for (int j = 0; j < 4; ++j) {
        const int e = tid + 128 * j;
        const float4* wp = (const float4*)(Wpk + (size_t)e * 32);
#pragma unroll
        for (int q = 0; q < 6; ++q) {
            const float4 v = wp[q];
            wrg[j][4*q] = v.x; wrg[j][4*q+1] = v.y; wrg[j][4*q+2] = v.z; wrg[j][4*q+3] = v.w;
        }
        const float4 t = wp[6];
        wrad[j] = t.x; brg[j] = t.y;
        za[j] = (e / 24) * 28 + (e % 24);
    }
    // union extra row: wave0 = redis row 512+l; wave1 = aux row min(l,48)
    float ext[32];
    {
        const float4* p = (const float4*)((wv == 0) ? (Wpk + (size_t)(512 + l) * 32)
                                                    : (Apk + (size_t)((l < 49) ? l : 48) * 32));
#pragma unroll
        for (int q = 0; q < 8; ++q) {
            const float4 v = p[q];
            ext[4*q] = v.x; ext[4*q+1] = v.y; ext[4*q+2] = v.z; ext[4*q+3] = v.w;
        }
    }
    const int za4 = ((512 + l) / 24) * 28 + (512 + l) % 24;

    const int rc = l >> 1, hh = l & 1;

    const float* xrow = X + (size_t)b * T_ * 4;
    const float* orow = ORY + (size_t)b * T_ * 7;

    if (tid < 24) cbuf[tid] = 0.f;
    __syncthreads();

    float Ncum = 0.f, rp = 0.f;
    float4 xc = *(const float4*)xrow;   // step-u X in registers
    float dvsc = orow[0];

    for (int u = 0; u <= NS_; ++u) {
        const bool do1 = (u < NS_), doCv = (u > 0);

        // prefetch step u+1 (hidden under the whole step)
        const int un = (u + 1 <= NS_) ? (u + 1) : NS_;
        const float4 xn = *(const float4*)(xrow + un * 4);
        const float dn = orow[un * 7];

        const float ra = xc.x;

        // C_u broadcast + kind1 multiplier captured pre-barrier
        float Cs[24];
#pragma unroll
        for (int q = 0; q < 6; ++q) {
            const float4 v = ((const float4*)cbuf)[q];
            Cs[4*q] = v.x; Cs[4*q+1] = v.y; Cs[4*q+2] = v.z; Cs[4*q+3] = v.w;
        }
        const float mlt1 = cbuf[rc];

        // ---- Phase A: shared dots (4 rows); z1 = D + wrad*ra, z2 = D + wrad*rp ----
#pragma unroll
        for (int j = 0; j < 4; ++j) {
            float p0 = brg[j], p1 = 0.f, p2 = 0.f, p3 = 0.f;
#pragma unroll
            for (int k = 0; k < 24; k += 4) {
                p0 = fmaf(wrg[j][k],   Cs[k],   p0);
                p1 = fmaf(wrg[j][k+1], Cs[k+1], p1);
                p2 = fmaf(wrg[j][k+2], Cs[k+2], p2);
                p3 = fmaf(wrg[j][k+3], Cs[k+3], p3);
            }
            const float D = (p0 + p1) + (p2 + p3);
            if (do1)  zb1[za[j]] = fmaf(wrad[j], ra, D);
            if (doCv) zb2[za[j]] = fmaf(wrad[j], rp, D);
        }

        if (wv == 0) {
            // 5th redis row (rows 512..575)
            float p0 = ext[25], p1 = 0.f, p2 = 0.f, p3 = 0.f;
#pragma unroll
            for (int k = 0; k < 24; k += 4) {
                p0 = fmaf(ext[k],   Cs[k],   p0);
                p1 = fmaf(ext[k+1], Cs[k+1], p1);
                p2 = fmaf(ext[k+2], Cs[k+2], p2);
                p3 = fmaf(ext[k+3], Cs[k+3], p3);
            }
            const float D = (p0 + p1) + (p2 + p3);
            if (do1)  zb1[za4] = fmaf(ext[24], ra, D);
            if (doCv) zb2[za4] = fmaf(ext[24], rp, D);
        } else if (do1) {
            // aux row + in-wave part/cons/assim -> cmid (lanes 0..23); z pre-scaled
            Ncum += xc.w;
            const float tave = 0.5f * (xc.y + xc.z);
            const float clm = fminf(fmaxf(tave * 50.f, 10.f), 40.f);
            const float eff = 0.54f - (clm - 10.f) * (0.18f / 30.f);
            const float cpot = ra * (eff * (2.f * 0.5f / 3.6f * (12.f / 44.f)));

            float z = ext[29];
#pragma unroll
            for (int k = 0; k < 24; ++k) z = fmaf(ext[k], Cs[k], z);
            z = fmaf(ext[24], dvsc, z);
            z = fmaf(ext[25], ra, z);
            z = fmaf(ext[26], xc.y, z);
            z = fmaf(ext[27], xc.z, z);
            z = fmaf(ext[28], Ncum, z);

            float pm = (l < 24) ? z : -1e30f;
#pragma unroll
            for (int o = 1; o < 32; o <<= 1) pm = fmaxf(pm, __shfl_xor(pm, o, 32));
            float pe = (l < 24) ? exp2f(z - pm) : 0.f;
            float ps = pe;
#pragma unroll
            for (int o = 1; o < 32; o <<= 1) ps += __shfl_xor(ps, o, 32);
            const float conz = __shfl(z, 24 + (l & 31), 64);
            const float asmz = __shfl(z, 48, 64);
            if (l < 24) {
                const float part = __fdividef(pe, ps);
                cmb[l] = (cbuf[l] + sigm2(asmz) * cpot * part) * (1.f - sigm2(conz));
            }
        }
        __syncthreads();   // B1: zb + cmb ready

        // ---- FUSED softmax + colsum: wave wv owns kind wv (same-wave LDS ordered) ----
        {
            const bool act = (l < 48) && (wv ? doCv : do1);
            if (act) {
                const float* zs = wv ? zb2 : zb1;
                float* pbk = wv ? pb2 : pb1;
                const float4* z4 = (const float4*)(zs + rc * 28 + hh * 12);
                float z[12];
#pragma unroll
                for (int q = 0; q < 3; ++q) {
                    const float4 v = z4[q];
                    z[4*q] = v.x; z[4*q+1] = v.y; z[4*q+2] = v.z; z[4*q+3] = v.w;
                }
                float m = z[0];
#pragma unroll
                for (int i = 1; i < 12; ++i) m = fmaxf(m, z[i]);
                m = fmaxf(m, __shfl_xor(m, 1));
                float ss = 0.f;
#pragma unroll
                for (int i = 0; i < 12; ++i) { z[i] = exp2f(z[i] - m); ss += z[i]; }
                ss += __shfl_xor(ss, 1);
                const float mult = wv ? mlt1 : cmb[rc];
                const float f = __fdividef(mult, ss);
#pragma unroll
                for (int i = 0; i < 12; ++i) pbk[(hh * 12 + i) * 28 + rc] = z[i] * f;

                // colsum (same-wave RAW; HW orders LDS ops within a wave)
                float ssum = 0.f;
                const float4* p4 = (const float4*)(pbk + rc * 28 + hh * 12);
#pragma unroll
                for (int i = 0; i < 3; ++i) {
                    const float4 v = p4[i];
                    ssum += (v.x + v.y) + (v.z + v.w);
                }
                ssum += __shfl_xor(ssum, 1);
                if (hh == 0) {
                    if (wv) {
                        Cconv[((size_t)b * NS_ + (u - 1)) * CD_ + rc] = ssum;
                    } else {
                        cbuf[rc] = ssum;
                        Ccell[((size_t)b * NS_ + u) * CD_ + rc] = ssum;
                    }
                }
            }
        }
        __syncthreads();   // B2: C(t+1) visible; zb free for next step
        rp = ra; xc = xn; dvsc = dn;
    }
}

// ---- epilogue: all_day from Ccell (streaming, trivially parallel) ----
__global__ __launch_bounds__(256) void mclstm_allday(
    const float* __restrict__ ORY, const float* __restrict__ c2a,
    const float* __restrict__ g2y, const float* __restrict__ Ccell,
    float* __restrict__ allday) {
    const int tid = blockIdx.x * 256 + threadIdx.x;
    if (tid < B_) {
#pragma unroll
        for (int k = 0; k < 7; ++k)
            allday[(size_t)tid * T_ * 7 + k] = ORY[(size_t)tid * T_ * 7 + k];
    }
    if (tid >= NTASK) return;
    const int b = tid / NS_;
    const int t = tid - b * NS_;

    const float* Cp = Ccell + (size_t)tid * CD_;
    float C[24];
#pragma unroll
    for (int q = 0; q < 6; ++q) {
        const float4 v = *(const float4*)(Cp + 4 * q);
        C[4 * q] = v.x; C[4 * q + 1] = v.y; C[4 * q + 2] = v.z; C[4 * q + 3] = v.w;
    }
    float pai = 0.f;
#pragma unroll
    for (int c = 0; c < 24; ++c) pai += fabsf(C[c] * c2a[c]);
    float lea = 0.f, ste = 0.f, gra = 0.f, yie = 0.f;
#pragma unroll
    for (int c = 0; c < 8; ++c) lea += C[c];
#pragma unroll
    for (int c = 8; c < 16; ++c) ste += C[c];
#pragma unroll
    for (int c = 16; c < 24; ++c) { gra += C[c]; yie += fabsf(C[c] * g2y[c - 16]); }
    lea /= 0.419f; ste /= 0.431f; gra /= 0.487f; yie /= 0.487f;
    const float agb = lea + ste + gra;

    float* ad = allday + ((size_t)b * T_ + (t + 1)) * 7;
    ad[0] = ORY[((size_t)b * T_ + (t + 1)) * 7];
    ad[1] = pai; ad[2] = lea; ad[3] = ste; ad[4] = gra; ad[5] = agb; ad[6] = yie;
}

extern "C" void kernel_launch(void* const* d_in, const int* in_sizes, int n_in,
                              void* d_out, int out_size, void* d_ws, size_t ws_size,
                              hipStream_t stream) {
    const float* X   = (const float*)d_in[0];
    const float* ORY = (const float*)d_in[1];
    const float* Wr  = (const float*)d_in[2];
    const float* br  = (const float*)d_in[3];
    const float* Wp  = (const float*)d_in[4];
    const float* bp  = (const float*)d_in[5];
    const float* Wc  = (const float*)d_in[6];
    const float* bc  = (const float*)d_in[7];
    const float* Wa  = (const float*)d_in[8];
    const float* ba  = (const float*)d_in[9];
    const float* c2a = (const float*)d_in[10];
    const float* g2y = (const float*)d_in[11];

    float* allday = (float*)d_out;
    float* Ccell  = allday + (size_t)B_ * T_ * 7;
    float* Cconv  = Ccell + (size_t)B_ * NS_ * CD_;

    float* Wpk = (float*)d_ws;            // 576*32 floats
    float* Apk = Wpk + 576 * 32;          // 49*32 floats

    hipLaunchKernelGGL(mclstm_pack, dim3(10), dim3(64), 0, stream,
                       Wr, br, Wp, bp, Wc, bc, Wa, ba, Wpk, Apk);
    hipLaunchKernelGGL(mclstm_main, dim3(B_), dim3(128), 0, stream,
                       X, ORY, Wpk, Apk, Ccell, Cconv);
    hipLaunchKernelGGL(mclstm_allday, dim3(NTASK / 256), dim3(256), 0, stream,
                       ORY, c2a, g2y, Ccell, allday);
}